// Round 5
// baseline (1272.263 us; speedup 1.0000x reference)
//
#include <hip/hip_runtime.h>
#include <math.h>

// ---------------- constants (match reference) ----------------
#define N_NODES 4096
#define D_IN    768
#define H1      384
#define H2      256
#define H3      512
#define D_OUT   128
#define E_EDGES 8192
#define K_MID   129
#define ALPHA   0.2f
#define NEGV    -9000000000000000.0f

typedef unsigned long long u64;
typedef unsigned short u16;
typedef __attribute__((ext_vector_type(8))) short bf16x8;
typedef __attribute__((ext_vector_type(4))) float f32x4;

// ---------------- helpers ----------------
__device__ __forceinline__ float eluf(float x) {          // precise (epilogues)
    return x > 0.f ? x : expm1f(x);
}

template<int ACT>  // 0 = leaky_relu(0.2), 1 = elu  (fast path, softmax logits)
__device__ __forceinline__ float actf(float x) {
    if (ACT == 0) return x >= 0.f ? x : ALPHA * x;
    else          return x > 0.f ? x : __expf(x) - 1.f;
}

__device__ __forceinline__ u16 f2bf(float f) {            // RNE fp32 -> bf16 bits
    unsigned u = __float_as_uint(f);
    unsigned r = (u + 0x7FFFu + ((u >> 16) & 1u)) >> 16;
    return (u16)r;
}
__device__ __forceinline__ float bf2f(u16 h) {
    return __uint_as_float(((unsigned)h) << 16);
}

__device__ __forceinline__ float waveReduceMax(float v) {
    #pragma unroll
    for (int off = 32; off; off >>= 1) v = fmaxf(v, __shfl_xor(v, off));
    return v;
}
__device__ __forceinline__ float waveReduceSum(float v) {
    #pragma unroll
    for (int off = 32; off; off >>= 1) v += __shfl_xor(v, off);
    return v;
}

// ---------------- zero fill ----------------
__global__ __launch_bounds__(256)
void zero_f32(float4* __restrict__ p, int n4) {
    int idx = blockIdx.x * 256 + threadIdx.x;
    int stride = gridDim.x * 256;
    float4 z = {0.f, 0.f, 0.f, 0.f};
    for (int i = idx; i < n4; i += stride) p[i] = z;
}

// ---------------- pack adj into bitmask ----------------
__global__ __launch_bounds__(256)
void pack_adj(const int* __restrict__ adj, u64* __restrict__ bits, int nwords) {
    int wid  = (blockIdx.x * 256 + threadIdx.x) >> 6;
    int lane = threadIdx.x & 63;
    int nw   = (gridDim.x * 256) >> 6;
    for (int w = wid; w < nwords; w += nw) {
        u64 m = __ballot(adj[((size_t)w << 6) + lane] > 0);
        if (lane == 0) bits[w] = m;
    }
}

// ---------------- generic transpose + cvt: dst[c][r] = bf16(src[r][c]) ----------------
struct TP { const float* s[3]; u16* d[3]; };
__global__ __launch_bounds__(256)
void transpose_cvt(TP tp, int R, int C)
{
    __shared__ float tile[64][65];
    const int z = blockIdx.z;
    const float* __restrict__ src = tp.s[z];
    u16* __restrict__ dst = tp.d[z];
    const int j0 = blockIdx.x * 64, c0 = blockIdx.y * 64;
    const int t = threadIdx.x;
    #pragma unroll
    for (int q = 0; q < 16; ++q) {
        int idx = q * 256 + t;
        int jl = idx >> 6, cl = idx & 63;
        tile[jl][cl] = src[(size_t)(j0 + jl) * C + c0 + cl];
    }
    __syncthreads();
    #pragma unroll
    for (int q = 0; q < 16; ++q) {
        int idx = q * 256 + t;
        int cl = idx >> 6, jl = idx & 63;
        dst[(size_t)(c0 + cl) * R + j0 + jl] = f2bf(tile[jl][cl]);
    }
}

// ---------------- Wa[ch][0/1][k] = sum_c W[ch][k][c] * a[ch][c or H1+c] ----------------
__global__ __launch_bounds__(256)
void wa_pre(const float* __restrict__ gat_W, const float* __restrict__ gat_a,
            float* __restrict__ Wa)
{
    const int ch = blockIdx.y;
    const int k  = blockIdx.x * 256 + threadIdx.x;        // 0..767
    const float* wr = gat_W + ((size_t)ch * D_IN + k) * H1;
    const float* a  = gat_a + (size_t)ch * 2 * H1;
    float w1 = 0.f, w2 = 0.f;
    for (int c = 0; c < H1; ++c) { float wv = wr[c]; w1 += wv * a[c]; w2 += wv * a[H1 + c]; }
    Wa[(size_t)ch * 2 * D_IN + k]        = w1;
    Wa[(size_t)ch * 2 * D_IN + D_IN + k] = w2;
}

// ---------------- x (fp32) -> xb (bf16, same layout) ----------------
struct XP3 { const float* x[3]; };
__global__ __launch_bounds__(256)
void cvt_x(XP3 xp, u16* __restrict__ xb)
{
    const int ch = blockIdx.y;
    const float* s = xp.x[ch];
    u16* d = xb + (size_t)ch * N_NODES * D_IN;
    const int n4 = N_NODES * D_IN / 4;
    for (int idx = blockIdx.x * 256 + threadIdx.x; idx < n4; idx += gridDim.x * 256) {
        float4 v = ((const float4*)s)[idx];
        unsigned lo = (unsigned)f2bf(v.x) | ((unsigned)f2bf(v.y) << 16);
        unsigned hi = (unsigned)f2bf(v.z) | ((unsigned)f2bf(v.w) << 16);
        ((uint2*)d)[idx] = make_uint2(lo, hi);
    }
}

// ---------------- s1/s2 = x @ Wa (fp32, exact logits) ----------------
__global__ __launch_bounds__(64)
void xdot(XP3 xp, const float* __restrict__ Wa,
          float* __restrict__ s1b, float* __restrict__ s2b)
{
    const int i = blockIdx.x, ch = blockIdx.y, lane = threadIdx.x;
    const float* xr = xp.x[ch] + (size_t)i * D_IN;
    const float* w1 = Wa + (size_t)ch * 2 * D_IN;
    const float* w2 = w1 + D_IN;
    float p1 = 0.f, p2 = 0.f;
    for (int k = lane; k < D_IN; k += 64) { float xv = xr[k]; p1 += xv * w1[k]; p2 += xv * w2[k]; }
    p1 = waveReduceSum(p1);
    p2 = waveReduceSum(p2);
    if (lane == 0) { s1b[ch * N_NODES + i] = p1; s2b[ch * N_NODES + i] = p2; }
}

// ---------------- batched row dots (core: hcore @ a_core) ----------------
__global__ __launch_bounds__(64)
void rowdot2(const float* __restrict__ hbase, size_t hStride,
             const float* __restrict__ ab, int K,
             float* __restrict__ s1b, float* __restrict__ s2b)
{
    const int i = blockIdx.x, z = blockIdx.y, lane = threadIdx.x;
    const float* hp = hbase + (size_t)z * hStride + (size_t)i * K;
    const float* a  = ab + (size_t)z * 2 * K;
    float p1 = 0.f, p2 = 0.f;
    for (int k = lane; k < K; k += 64) {
        float hv = hp[k];
        p1 += hv * a[k];
        p2 += hv * a[K + k];
    }
    p1 = waveReduceSum(p1);
    p2 = waveReduceSum(p2);
    if (lane == 0) { s1b[z * N_NODES + i] = p1; s2b[z * N_NODES + i] = p2; }
}

// ---------------- per-row softmax stats: q[z][i] = M + ln(Z) ----------------
template<int ACT>
__global__ __launch_bounds__(256)
void softmax_stats(const float* __restrict__ s1b, const float* __restrict__ s2b,
                   const u64* __restrict__ bits, float* __restrict__ qb)
{
    __shared__ float lsh[N_NODES];
    __shared__ float red[8];
    const int i = blockIdx.x, z = blockIdx.y, t = threadIdx.x;
    const float s1v = s1b[z * N_NODES + i];
    const float* s2 = s2b + (size_t)z * N_NODES;
    float mx = -3.0e38f;
    for (int j = t; j < N_NODES; j += 256) {
        u64 wd = bits[((size_t)i << 6) + (j >> 6)];
        float l = ((wd >> (j & 63)) & 1ull) ? actf<ACT>(s1v + s2[j]) : NEGV;
        lsh[j] = l;
        mx = fmaxf(mx, l);
    }
    mx = waveReduceMax(mx);
    if ((t & 63) == 0) red[t >> 6] = mx;
    __syncthreads();
    float M = fmaxf(fmaxf(red[0], red[1]), fmaxf(red[2], red[3]));
    float sum = 0.f;
    for (int j = t; j < N_NODES; j += 256) sum += __expf(lsh[j] - M);
    sum = waveReduceSum(sum);
    if ((t & 63) == 0) red[4 + (t >> 6)] = sum;
    __syncthreads();
    if (t == 0) {
        float Z = red[4] + red[5] + red[6] + red[7];
        qb[z * N_NODES + i] = M + logf(Z);
    }
}

// ---------------- generic bf16 MFMA GEMM: D[m][n] = sum_k A[m][k]*B[n][k] ----------------
// A: [M][K] bf16 k-contig.  B: [N][K] bf16 k-contig.  out[n*ldo + m] (m contiguous).
// EP: 0 raw fp32 | 1 elu(v+bias[m]) bf16 | 2 elu(v+bias[m]) fp32 | 3 raw bf16
struct GB {
    const u16* A[3];
    const u16* B[3];
    const float* bias[3];
    void* C[3];
};
template<int EP>
__global__ __launch_bounds__(256)
void gemm_bf16(GB gb, int K, int ldo)
{
    __shared__ u16 Al[128 * 64];
    __shared__ u16 Bl[128 * 64];
    const int z = blockIdx.z;
    const u16* __restrict__ A = gb.A[z];
    const u16* __restrict__ B = gb.B[z];
    const int t  = threadIdx.x;
    const int m0 = blockIdx.x * 128, n0 = blockIdx.y * 128;
    const int lane = t & 63, wv = t >> 6;
    const int l15 = lane & 15, l4 = lane >> 4;
    const int mrow0 = 64 * (wv & 1), nrow0 = 64 * (wv >> 1);
    const int sblk = t & 7, srow = t >> 3;
    f32x4 acc[4][4] = {};

    for (int k0 = 0; k0 < K; k0 += 64) {
        __syncthreads();
        #pragma unroll
        for (int q = 0; q < 4; ++q) {
            const int row = srow + (q << 5);
            const uint4 va = *(const uint4*)(A + (size_t)(m0 + row) * K + k0 + (sblk << 3));
            *(uint4*)&Al[row * 64 + ((sblk << 3) ^ ((row & 7) << 3))] = va;
            const uint4 vb = *(const uint4*)(B + (size_t)(n0 + row) * K + k0 + (sblk << 3));
            *(uint4*)&Bl[row * 64 + ((sblk << 3) ^ ((row & 7) << 3))] = vb;
        }
        __syncthreads();
        #pragma unroll
        for (int kk = 0; kk < 2; ++kk) {
            bf16x8 af[4], bfr[4];
            const int colu = (l4 << 3) + (kk << 5);
            #pragma unroll
            for (int r = 0; r < 4; ++r) {
                const int row = mrow0 + (r << 4) + l15;
                af[r] = *(const bf16x8*)&Al[row * 64 + (colu ^ ((row & 7) << 3))];
            }
            #pragma unroll
            for (int n = 0; n < 4; ++n) {
                const int row = nrow0 + (n << 4) + l15;
                bfr[n] = *(const bf16x8*)&Bl[row * 64 + (colu ^ ((row & 7) << 3))];
            }
            #pragma unroll
            for (int r = 0; r < 4; ++r)
                #pragma unroll
                for (int n = 0; n < 4; ++n)
                    acc[r][n] = __builtin_amdgcn_mfma_f32_16x16x32_bf16(af[r], bfr[n], acc[r][n], 0, 0, 0);
        }
    }
    const float* bias = gb.bias[z];
    #pragma unroll
    for (int n = 0; n < 4; ++n) {
        const int nn = n0 + nrow0 + (n << 4) + l15;
        #pragma unroll
        for (int r = 0; r < 4; ++r) {
            const int mm = m0 + mrow0 + (r << 4) + (l4 << 2);
            f32x4 v = acc[r][n];
            if (EP == 1 || EP == 2) {
                #pragma unroll
                for (int j = 0; j < 4; ++j) v[j] = eluf(v[j] + bias[mm + j]);
            }
            if (EP == 1 || EP == 3) {
                unsigned lo = (unsigned)f2bf(v[0]) | ((unsigned)f2bf(v[1]) << 16);
                unsigned hi = (unsigned)f2bf(v[2]) | ((unsigned)f2bf(v[3]) << 16);
                *(uint2*)((u16*)gb.C[z] + (size_t)nn * ldo + mm) = make_uint2(lo, hi);
            } else {
                *(f32x4*)((float*)gb.C[z] + (size_t)nn * ldo + mm) = v;
            }
        }
    }
}

// ---------------- MFMA att with on-the-fly weights + atomic accumulate ----------------
// out[i][c] += sum_j (sum_hd att_hd[i][j]) hT[c][j]   (atomics over j-chunks)
template<int ACT, int NH>
__global__ __launch_bounds__(256)
void att_mfma(const u16* __restrict__ hT, const float* __restrict__ s1b,
              const float* __restrict__ s2b, const float* __restrict__ qb,
              const u64* __restrict__ bits, float* __restrict__ out, int Ncols)
{
    __shared__ u16 Wl[128 * 64];
    __shared__ u16 Al[128 * 64];
    __shared__ float s1s[NH][128];
    __shared__ float qs[NH][128];
    const int t    = threadIdx.x;
    const int i0   = blockIdx.x * 128;
    const int c0   = blockIdx.y * 128;
    const int ch   = blockIdx.z >> 3;
    const int jt0  = (blockIdx.z & 7) * 8;
    const int lane = t & 63, wv = t >> 6;
    const int l15  = lane & 15, l4 = lane >> 4;
    const int sblk = t & 7, srow = t >> 3;
    const float* s1p = s1b + (size_t)ch * NH * N_NODES;
    const float* s2p = s2b + (size_t)ch * NH * N_NODES;
    const float* qp  = qb  + (size_t)ch * NH * N_NODES;
    const u16* hTp   = hT  + (size_t)ch * Ncols * N_NODES;
    float* op        = out + (size_t)ch * N_NODES * Ncols;

    for (int u = t; u < NH * 128; u += 256) {
        int hd = u >> 7, iL = u & 127;
        s1s[hd][iL] = s1p[hd * N_NODES + i0 + iL];
        qs[hd][iL]  = qp[hd * N_NODES + i0 + iL];
    }

    f32x4 acc[4][4] = {};
    const int mrow0 = 64 * (wv & 1);      // c-dim base
    const int nrow0 = 64 * (wv >> 1);     // i-dim base

    for (int jt = jt0; jt < jt0 + 8; ++jt) {
        const int j0 = jt << 6;
        __syncthreads();
        // phase W: generate combined softmax weights -> Wl (rows = iL, cols = j)
        float s2v[NH];
        #pragma unroll
        for (int hd = 0; hd < NH; ++hd) s2v[hd] = s2p[hd * N_NODES + j0 + lane];
        #pragma unroll 4
        for (int rr = 0; rr < 32; ++rr) {
            const int iL = (rr << 2) | wv;
            const u64 wd = bits[((size_t)(i0 + iL) << 6) + jt];
            float w = 0.f;
            if ((wd >> lane) & 1ull) {
                #pragma unroll
                for (int hd = 0; hd < NH; ++hd)
                    w += __expf(actf<ACT>(s1s[hd][iL] + s2v[hd]) - qs[hd][iL]);
            }
            Wl[iL * 64 + (lane ^ ((iL & 7) << 3))] = f2bf(w);
        }
        // phase A: stage hT[c0..+128][j0..+64]
        #pragma unroll
        for (int q = 0; q < 4; ++q) {
            const int row = srow + (q << 5);
            const uint4 v = *(const uint4*)(hTp + (size_t)(c0 + row) * N_NODES + j0 + (sblk << 3));
            *(uint4*)&Al[row * 64 + ((sblk << 3) ^ ((row & 7) << 3))] = v;
        }
        __syncthreads();
        // phase MFMA
        #pragma unroll
        for (int kk = 0; kk < 2; ++kk) {
            bf16x8 af[4], bfr[4];
            const int colu = (l4 << 3) + (kk << 5);
            #pragma unroll
            for (int r = 0; r < 4; ++r) {
                const int row = mrow0 + (r << 4) + l15;
                af[r] = *(const bf16x8*)&Al[row * 64 + (colu ^ ((row & 7) << 3))];
            }
            #pragma unroll
            for (int n = 0; n < 4; ++n) {
                const int row = nrow0 + (n << 4) + l15;
                bfr[n] = *(const bf16x8*)&Wl[row * 64 + (colu ^ ((row & 7) << 3))];
            }
            #pragma unroll
            for (int r = 0; r < 4; ++r)
                #pragma unroll
                for (int n = 0; n < 4; ++n)
                    acc[r][n] = __builtin_amdgcn_mfma_f32_16x16x32_bf16(af[r], bfr[n], acc[r][n], 0, 0, 0);
        }
    }
    // atomic epilogue
    #pragma unroll
    for (int n = 0; n < 4; ++n) {
        const int i = i0 + nrow0 + (n << 4) + l15;
        #pragma unroll
        for (int r = 0; r < 4; ++r) {
            const int c = c0 + mrow0 + (r << 4) + (l4 << 2);
            #pragma unroll
            for (int j = 0; j < 4; ++j)
                unsafeAtomicAdd(&op[(size_t)i * Ncols + c + j], acc[r][n][j]);
        }
    }
}

// ---------------- GAT reduce (all 3 ch): xacc = sum_ch l2norm(elu(0.99g+0.01h)) + b ----------------
__global__ __launch_bounds__(128)
void reduce_gat_all(const float* __restrict__ gout3, const u16* __restrict__ hT,
                    const float* __restrict__ gat_b, float* __restrict__ xacc)
{
    __shared__ float red[3][2];
    const int i = blockIdx.x, t = threadIdx.x;
    float v[3][3];
    #pragma unroll
    for (int ch = 0; ch < 3; ++ch) {
        const float* gp = gout3 + ((size_t)ch * N_NODES + i) * H1;
        const u16*   hp = hT + (size_t)ch * H1 * N_NODES;
        float ss = 0.f;
        #pragma unroll
        for (int u = 0; u < 3; ++u) {
            const int c = t + u * 128;
            float hv = bf2f(hp[(size_t)c * N_NODES + i]);
            float vv = eluf(0.99f * gp[c] + 0.01f * hv);
            v[ch][u] = vv; ss += vv * vv;
        }
        ss = waveReduceSum(ss);
        if ((t & 63) == 0) red[ch][t >> 6] = ss;
    }
    __syncthreads();
    float inv[3];
    #pragma unroll
    for (int ch = 0; ch < 3; ++ch)
        inv[ch] = 1.f / fmaxf(sqrtf(red[ch][0] + red[ch][1]), 1e-12f);
    #pragma unroll
    for (int u = 0; u < 3; ++u) {
        const int c = t + u * 128;
        float o = 0.f;
        #pragma unroll
        for (int ch = 0; ch < 3; ++ch)
            o += v[ch][u] * inv[ch] + gat_b[ch * H1 + c];
        xacc[(size_t)i * H1 + c] = o;
    }
}

// ---------------- conv(K=129, 3 ch) + elu + channel-combine -> hcore ----------------
__global__ __launch_bounds__(256)
void conv_combine(const float* __restrict__ xacc, const float* __restrict__ w_mid,
                  const float* __restrict__ b_mid, const float* __restrict__ w_core,
                  const float* __restrict__ b_core, float* __restrict__ hcore)
{
    __shared__ float row[H1];
    __shared__ float wm[3 * K_MID];
    const int n = blockIdx.x, t = threadIdx.x;
    for (int k = t; k < H1; k += 256) row[k] = eluf(xacc[(size_t)n * H1 + k] * (1.f / 3.f));
    for (int k = t; k < 3 * K_MID; k += 256) wm[k] = w_mid[k];
    __syncthreads();
    const int w = t;
    float a0 = 0.f, a1 = 0.f, a2 = 0.f;
    for (int k = 0; k < K_MID; ++k) {
        float xv = row[w + k];
        a0 += xv * wm[k];
        a1 += xv * wm[K_MID + k];
        a2 += xv * wm[2 * K_MID + k];
    }
    float hv = eluf(a0 + b_mid[0]) * w_core[0]
             + eluf(a1 + b_mid[1]) * w_core[1]
             + eluf(a2 + b_mid[2]) * w_core[2] + b_core[0];
    hcore[(size_t)n * H2 + w] = hv;
}

// ---------------- core reduce: embed_bf = bf16(l2norm(elu(0.125*hpass+0.5*hcore)) + cbias) ----------------
__global__ __launch_bounds__(256)
void reduce_core(const float* __restrict__ hpass, const float* __restrict__ hcore,
                 const float* __restrict__ cbias, u16* __restrict__ embed_bf)
{
    __shared__ float red[4];
    const int i = blockIdx.x, t = threadIdx.x;
    float v = eluf(0.125f * hpass[(size_t)i * H2 + t] + 0.5f * hcore[(size_t)i * H2 + t]);
    float ss = waveReduceSum(v * v);
    if ((t & 63) == 0) red[t >> 6] = ss;
    __syncthreads();
    float inv = 1.f / fmaxf(sqrtf(red[0] + red[1] + red[2] + red[3]), 1e-12f);
    embed_bf[(size_t)i * H2 + t] = f2bf(v * inv + cbias[t]);
}

// ---------------- pred[e] = tf[src[e]] . tg[dst[e]] ----------------
__global__ __launch_bounds__(256)
void gather_dot(const float* __restrict__ tf, const float* __restrict__ tg,
                const int* __restrict__ ts, float* __restrict__ pred)
{
    const int e = blockIdx.x * 4 + (threadIdx.x >> 6);
    const int lane = threadIdx.x & 63;
    const int i0 = ts[(size_t)e * 2], i1 = ts[(size_t)e * 2 + 1];
    const float* a = tf + (size_t)i0 * D_OUT;
    const float* b = tg + (size_t)i1 * D_OUT;
    float p = a[lane] * b[lane] + a[lane + 64] * b[lane + 64];
    p = waveReduceSum(p);
    if (lane == 0) pred[e] = p;
}

// ---------------- launch ----------------
extern "C" void kernel_launch(void* const* d_in, const int* in_sizes, int n_in,
                              void* d_out, int out_size, void* d_ws, size_t ws_size,
                              hipStream_t stream)
{
    const float* x1     = (const float*)d_in[0];
    const float* x2     = (const float*)d_in[1];
    const float* x3     = (const float*)d_in[2];
    const int*   adj    = (const int*)d_in[3];
    const int*   ts     = (const int*)d_in[4];
    const float* gat_W  = (const float*)d_in[5];
    const float* gat_a  = (const float*)d_in[6];
    const float* gat_b  = (const float*)d_in[7];
    const float* w_mid  = (const float*)d_in[8];
    const float* b_mid  = (const float*)d_in[9];
    const float* w_core = (const float*)d_in[10];
    const float* b_core = (const float*)d_in[11];
    const float* a_core = (const float*)d_in[12];
    const float* cbias  = (const float*)d_in[13];
    const float* W_tf1  = (const float*)d_in[14];
    const float* b_tf1  = (const float*)d_in[15];
    const float* W_tf2  = (const float*)d_in[16];
    const float* b_tf2  = (const float*)d_in[17];
    const float* W_tg1  = (const float*)d_in[18];
    const float* b_tg1  = (const float*)d_in[19];
    const float* W_tg2  = (const float*)d_in[20];
    const float* b_tg2  = (const float*)d_in[21];

    // ---- workspace layout (float units), ~47 MB ----
    const int NWORDS = N_NODES * (N_NODES / 64);        // 262144 u64
    float* fw    = (float*)d_ws;
    u64*   bits  = (u64*)d_ws;                          // 524288 fl
    float* s1b   = fw + 524288;                         // 16384
    float* s2b   = s1b + 16384;
    float* qb    = s2b + 16384;
    float* BIG   = qb + 16384;                          // 4718592 fl (xb | gout3 | t1/tf/tg)
    float* hpass = BIG + 4718592;                       // 1048576
    float* hTF   = hpass + 1048576;                     // 2359296 (hT | hcoreT+embed_bf)
    float* xacc  = hTF + 2359296;                       // 1572864
    float* hcore = xacc + 1572864;                      // 1048576
    float* WTgF  = hcore + 1048576;                     // 442368 (WTg | WT_mlp)
    float* Wa    = WTgF + 442368;                       // 4608

    u16* xb      = (u16*)BIG;                           // 3 x 4096x768 bf16
    float* gout3 = BIG;                                 // 3 x 4096x384 fp32
    u16* t1tf    = (u16*)BIG;                           // 4096x512 bf16
    u16* t1tg    = (u16*)(BIG + 1048576);
    float* tf    = BIG + 2097152;                       // 4096x128 fp32
    float* tg    = BIG + 2621440;
    u16* hT      = (u16*)hTF;                           // 3 x 384x4096 bf16
    u16* hcoreT  = (u16*)hTF;                           // 256x4096 bf16 (after GAT)
    u16* embed_bf= (u16*)(hTF + 524288);                // 4096x256 bf16
    u16* WTg     = (u16*)WTgF;                          // 3 x 384x768 bf16
    u16* WT1tf   = WTg;                                 // after gemm_h: 512x256
    u16* WT1tg   = WTg + 131072;
    u16* WT2tf   = WTg + 262144;                        // 128x512
    u16* WT2tg   = WTg + 327680;
    float* pred  = (float*)d_out;

    const dim3 blk(256);
    const size_t HSZ = (size_t)N_NODES * H1;

    // ---- prep ----
    pack_adj<<<dim3(1024), blk, 0, stream>>>(adj, bits, NWORDS);
    {   // gat_W -> WTg (bf16, [c][k])
        TP tp; for (int c = 0; c < 3; ++c) { tp.s[c] = gat_W + (size_t)c * D_IN * H1; tp.d[c] = WTg + (size_t)c * H1 * D_IN; }
        transpose_cvt<<<dim3(12, 6, 3), blk, 0, stream>>>(tp, D_IN, H1);
    }
    wa_pre<<<dim3(3, 3), blk, 0, stream>>>(gat_W, gat_a, Wa);
    XP3 xp; xp.x[0] = x1; xp.x[1] = x2; xp.x[2] = x3;
    cvt_x<<<dim3(768, 3), blk, 0, stream>>>(xp, xb);

    // ---- h^T = (x @ W)^T in bf16 via MFMA ----
    {
        GB gb;
        for (int c = 0; c < 3; ++c) {
            gb.A[c] = xb + (size_t)c * N_NODES * D_IN;
            gb.B[c] = WTg + (size_t)c * H1 * D_IN;
            gb.bias[c] = nullptr;
            gb.C[c] = hT + (size_t)c * HSZ;
        }
        gemm_bf16<3><<<dim3(32, 3, 3), blk, 0, stream>>>(gb, D_IN, N_NODES);
    }
    {   // mlp weight transposes (WTg region now reusable)
        TP tp; tp.s[0] = W_tf1; tp.s[1] = W_tg1; tp.d[0] = WT1tf; tp.d[1] = WT1tg;
        transpose_cvt<<<dim3(4, 8, 2), blk, 0, stream>>>(tp, H2, H3);
        TP tq; tq.s[0] = W_tf2; tq.s[1] = W_tg2; tq.d[0] = WT2tf; tq.d[1] = WT2tg;
        transpose_cvt<<<dim3(8, 2, 2), blk, 0, stream>>>(tq, H3, D_OUT);
    }

    // ---- GAT logits (exact fp32 via x @ (W@a)) + stats ----
    xdot<<<dim3(N_NODES, 3), dim3(64), 0, stream>>>(xp, Wa, s1b, s2b);
    softmax_stats<0><<<dim3(N_NODES, 3), blk, 0, stream>>>(s1b, s2b, bits, qb);

    // ---- zero accumulators (gout3 + hpass contiguous) ----
    zero_f32<<<dim3(2048), blk, 0, stream>>>((float4*)gout3, (int)((4718592 + 1048576) / 4));

    // ---- GAT attention (3 channels batched, atomic accumulate) ----
    att_mfma<0, 1><<<dim3(32, 3, 24), blk, 0, stream>>>(hT, s1b, s2b, qb, bits, gout3, H1);
    reduce_gat_all<<<dim3(N_NODES), dim3(128), 0, stream>>>(gout3, hT, gat_b, xacc);

    // ---- conv + combine ----
    conv_combine<<<dim3(N_NODES), blk, 0, stream>>>(xacc, w_mid, b_mid, w_core, b_core, hcore);

    // ---- core attention (4 heads collapsed) ----
    rowdot2<<<dim3(N_NODES, 4), dim3(64), 0, stream>>>(hcore, 0, a_core, H2, s1b, s2b);
    softmax_stats<1><<<dim3(N_NODES, 4), blk, 0, stream>>>(s1b, s2b, bits, qb);
    {
        TP tp; tp.s[0] = hcore; tp.d[0] = hcoreT;
        transpose_cvt<<<dim3(64, 4, 1), blk, 0, stream>>>(tp, N_NODES, H2);
    }
    att_mfma<1, 4><<<dim3(32, 2, 8), blk, 0, stream>>>(hcoreT, s1b, s2b, qb, bits, hpass, H2);
    reduce_core<<<dim3(N_NODES), blk, 0, stream>>>(hpass, hcore, cbias, embed_bf);

    // ---- final MLPs (bf16 MFMA, tf/tg batched) ----
    {
        GB gb;
        gb.A[0] = WT1tf; gb.A[1] = WT1tg;
        gb.B[0] = embed_bf; gb.B[1] = embed_bf;
        gb.bias[0] = b_tf1; gb.bias[1] = b_tg1;
        gb.C[0] = t1tf; gb.C[1] = t1tg;
        gemm_bf16<1><<<dim3(4, 32, 2), blk, 0, stream>>>(gb, H2, H3);
    }
    {
        GB gb;
        gb.A[0] = WT2tf; gb.A[1] = WT2tg;
        gb.B[0] = t1tf; gb.B[1] = t1tg;
        gb.bias[0] = b_tf2; gb.bias[1] = b_tg2;
        gb.C[0] = tf; gb.C[1] = tg;
        gemm_bf16<2><<<dim3(1, 32, 2), blk, 0, stream>>>(gb, H3, D_OUT);
    }
    gather_dot<<<dim3(E_EDGES / 4), blk, 0, stream>>>(tf, tg, ts, pred);
}

// Round 7
// 848.118 us; speedup vs baseline: 1.5001x; 1.5001x over previous
//
#include <hip/hip_runtime.h>
#include <math.h>

// ---------------- constants (match reference) ----------------
#define N_NODES 4096
#define D_IN    768
#define H1      384
#define H2      256
#define H3      512
#define D_OUT   128
#define E_EDGES 8192
#define K_MID   129
#define ALPHA   0.2f
#define NEGV    -9000000000000000.0f

typedef unsigned long long u64;
typedef unsigned short u16;
typedef __attribute__((ext_vector_type(8))) short bf16x8;
typedef __attribute__((ext_vector_type(4))) float f32x4;

// ---------------- helpers ----------------
__device__ __forceinline__ float eluf(float x) {          // precise (epilogues)
    return x > 0.f ? x : expm1f(x);
}

template<int ACT>  // 0 = leaky_relu(0.2), 1 = elu  (fast path, softmax logits)
__device__ __forceinline__ float actf(float x) {
    if (ACT == 0) return x >= 0.f ? x : ALPHA * x;
    else          return x > 0.f ? x : __expf(x) - 1.f;
}

__device__ __forceinline__ u16 f2bf(float f) {            // RNE fp32 -> bf16 bits
    unsigned u = __float_as_uint(f);
    unsigned r = (u + 0x7FFFu + ((u >> 16) & 1u)) >> 16;
    return (u16)r;
}
__device__ __forceinline__ float bf2f(u16 h) {
    return __uint_as_float(((unsigned)h) << 16);
}

__device__ __forceinline__ float waveReduceMax(float v) {
    #pragma unroll
    for (int off = 32; off; off >>= 1) v = fmaxf(v, __shfl_xor(v, off));
    return v;
}
__device__ __forceinline__ float waveReduceSum(float v) {
    #pragma unroll
    for (int off = 32; off; off >>= 1) v += __shfl_xor(v, off);
    return v;
}

// ---------------- pack adj into bitmask ----------------
__global__ __launch_bounds__(256)
void pack_adj(const int* __restrict__ adj, u64* __restrict__ bits, int nwords) {
    int wid  = (blockIdx.x * 256 + threadIdx.x) >> 6;
    int lane = threadIdx.x & 63;
    int nw   = (gridDim.x * 256) >> 6;
    for (int w = wid; w < nwords; w += nw) {
        u64 m = __ballot(adj[((size_t)w << 6) + lane] > 0);
        if (lane == 0) bits[w] = m;
    }
}

// ---------------- generic transpose + cvt: dst[c][r] = bf16(src[r][c]) ----------------
struct TP { const float* s[3]; u16* d[3]; };
__global__ __launch_bounds__(256)
void transpose_cvt(TP tp, int R, int C)
{
    __shared__ float tile[64][65];
    const int z = blockIdx.z;
    const float* __restrict__ src = tp.s[z];
    u16* __restrict__ dst = tp.d[z];
    const int j0 = blockIdx.x * 64, c0 = blockIdx.y * 64;
    const int t = threadIdx.x;
    #pragma unroll
    for (int q = 0; q < 16; ++q) {
        int idx = q * 256 + t;
        int jl = idx >> 6, cl = idx & 63;
        tile[jl][cl] = src[(size_t)(j0 + jl) * C + c0 + cl];
    }
    __syncthreads();
    #pragma unroll
    for (int q = 0; q < 16; ++q) {
        int idx = q * 256 + t;
        int cl = idx >> 6, jl = idx & 63;
        dst[(size_t)(c0 + cl) * R + j0 + jl] = f2bf(tile[jl][cl]);
    }
}

// ---------------- Wa[ch][0/1][k] = sum_c W[ch][k][c] * a[ch][c or H1+c] ----------------
__global__ __launch_bounds__(256)
void wa_pre(const float* __restrict__ gat_W, const float* __restrict__ gat_a,
            float* __restrict__ Wa)
{
    const int ch = blockIdx.y;
    const int k  = blockIdx.x * 256 + threadIdx.x;        // 0..767
    const float* wr = gat_W + ((size_t)ch * D_IN + k) * H1;
    const float* a  = gat_a + (size_t)ch * 2 * H1;
    float w1 = 0.f, w2 = 0.f;
    for (int c = 0; c < H1; ++c) { float wv = wr[c]; w1 += wv * a[c]; w2 += wv * a[H1 + c]; }
    Wa[(size_t)ch * 2 * D_IN + k]        = w1;
    Wa[(size_t)ch * 2 * D_IN + D_IN + k] = w2;
}

// ---------------- x (fp32) -> xb (bf16, same layout) ----------------
struct XP3 { const float* x[3]; };
__global__ __launch_bounds__(256)
void cvt_x(XP3 xp, u16* __restrict__ xb)
{
    const int ch = blockIdx.y;
    const float* s = xp.x[ch];
    u16* d = xb + (size_t)ch * N_NODES * D_IN;
    const int n4 = N_NODES * D_IN / 4;
    for (int idx = blockIdx.x * 256 + threadIdx.x; idx < n4; idx += gridDim.x * 256) {
        float4 v = ((const float4*)s)[idx];
        unsigned lo = (unsigned)f2bf(v.x) | ((unsigned)f2bf(v.y) << 16);
        unsigned hi = (unsigned)f2bf(v.z) | ((unsigned)f2bf(v.w) << 16);
        ((uint2*)d)[idx] = make_uint2(lo, hi);
    }
}

// ---------------- s1/s2 = x @ Wa (fp32, exact logits) ----------------
__global__ __launch_bounds__(64)
void xdot(XP3 xp, const float* __restrict__ Wa,
          float* __restrict__ s1b, float* __restrict__ s2b)
{
    const int i = blockIdx.x, ch = blockIdx.y, lane = threadIdx.x;
    const float* xr = xp.x[ch] + (size_t)i * D_IN;
    const float* w1 = Wa + (size_t)ch * 2 * D_IN;
    const float* w2 = w1 + D_IN;
    float p1 = 0.f, p2 = 0.f;
    for (int k = lane; k < D_IN; k += 64) { float xv = xr[k]; p1 += xv * w1[k]; p2 += xv * w2[k]; }
    p1 = waveReduceSum(p1);
    p2 = waveReduceSum(p2);
    if (lane == 0) { s1b[ch * N_NODES + i] = p1; s2b[ch * N_NODES + i] = p2; }
}

// ---------------- batched row dots (core: hcore @ a_core) ----------------
__global__ __launch_bounds__(64)
void rowdot2(const float* __restrict__ hbase, size_t hStride,
             const float* __restrict__ ab, int K,
             float* __restrict__ s1b, float* __restrict__ s2b)
{
    const int i = blockIdx.x, z = blockIdx.y, lane = threadIdx.x;
    const float* hp = hbase + (size_t)z * hStride + (size_t)i * K;
    const float* a  = ab + (size_t)z * 2 * K;
    float p1 = 0.f, p2 = 0.f;
    for (int k = lane; k < K; k += 64) {
        float hv = hp[k];
        p1 += hv * a[k];
        p2 += hv * a[K + k];
    }
    p1 = waveReduceSum(p1);
    p2 = waveReduceSum(p2);
    if (lane == 0) { s1b[z * N_NODES + i] = p1; s2b[z * N_NODES + i] = p2; }
}

// ---------------- per-row softmax stats: q[z][i] = M + ln(Z) ----------------
template<int ACT>
__global__ __launch_bounds__(256)
void softmax_stats(const float* __restrict__ s1b, const float* __restrict__ s2b,
                   const u64* __restrict__ bits, float* __restrict__ qb)
{
    __shared__ float lsh[N_NODES];
    __shared__ float red[8];
    const int i = blockIdx.x, z = blockIdx.y, t = threadIdx.x;
    const float s1v = s1b[z * N_NODES + i];
    const float* s2 = s2b + (size_t)z * N_NODES;
    float mx = -3.0e38f;
    for (int j = t; j < N_NODES; j += 256) {
        u64 wd = bits[((size_t)i << 6) + (j >> 6)];
        float l = ((wd >> (j & 63)) & 1ull) ? actf<ACT>(s1v + s2[j]) : NEGV;
        lsh[j] = l;
        mx = fmaxf(mx, l);
    }
    mx = waveReduceMax(mx);
    if ((t & 63) == 0) red[t >> 6] = mx;
    __syncthreads();
    float M = fmaxf(fmaxf(red[0], red[1]), fmaxf(red[2], red[3]));
    float sum = 0.f;
    for (int j = t; j < N_NODES; j += 256) sum += __expf(lsh[j] - M);
    sum = waveReduceSum(sum);
    if ((t & 63) == 0) red[4 + (t >> 6)] = sum;
    __syncthreads();
    if (t == 0) {
        float Z = red[4] + red[5] + red[6] + red[7];
        qb[z * N_NODES + i] = M + logf(Z);
    }
}

// ---------------- generic bf16 MFMA GEMM: D[m][n] = sum_k A[m][k]*B[n][k] ----------------
// A: [M][K] bf16 k-contig.  B: [N][K] bf16 k-contig.  out[n*ldo + m] (m contiguous).
// EP: 0 raw fp32 | 1 elu(v+bias[m]) bf16 | 2 elu(v+bias[m]) fp32 | 3 raw bf16
struct GB {
    const u16* A[3];
    const u16* B[3];
    const float* bias[3];
    void* C[3];
};
template<int EP>
__global__ __launch_bounds__(256)
void gemm_bf16(GB gb, int K, int ldo)
{
    __shared__ u16 Al[128 * 64];
    __shared__ u16 Bl[128 * 64];
    const int z = blockIdx.z;
    const u16* __restrict__ A = gb.A[z];
    const u16* __restrict__ B = gb.B[z];
    const int t  = threadIdx.x;
    const int m0 = blockIdx.x * 128, n0 = blockIdx.y * 128;
    const int lane = t & 63, wv = t >> 6;
    const int l15 = lane & 15, l4 = lane >> 4;
    const int mrow0 = 64 * (wv & 1), nrow0 = 64 * (wv >> 1);
    const int sblk = t & 7, srow = t >> 3;
    f32x4 acc[4][4] = {};

    for (int k0 = 0; k0 < K; k0 += 64) {
        __syncthreads();
        #pragma unroll
        for (int q = 0; q < 4; ++q) {
            const int row = srow + (q << 5);
            const uint4 va = *(const uint4*)(A + (size_t)(m0 + row) * K + k0 + (sblk << 3));
            *(uint4*)&Al[row * 64 + ((sblk << 3) ^ ((row & 7) << 3))] = va;
            const uint4 vb = *(const uint4*)(B + (size_t)(n0 + row) * K + k0 + (sblk << 3));
            *(uint4*)&Bl[row * 64 + ((sblk << 3) ^ ((row & 7) << 3))] = vb;
        }
        __syncthreads();
        #pragma unroll
        for (int kk = 0; kk < 2; ++kk) {
            bf16x8 af[4], bfr[4];
            const int colu = (l4 << 3) + (kk << 5);
            #pragma unroll
            for (int r = 0; r < 4; ++r) {
                const int row = mrow0 + (r << 4) + l15;
                af[r] = *(const bf16x8*)&Al[row * 64 + (colu ^ ((row & 7) << 3))];
            }
            #pragma unroll
            for (int n = 0; n < 4; ++n) {
                const int row = nrow0 + (n << 4) + l15;
                bfr[n] = *(const bf16x8*)&Bl[row * 64 + (colu ^ ((row & 7) << 3))];
            }
            #pragma unroll
            for (int r = 0; r < 4; ++r)
                #pragma unroll
                for (int n = 0; n < 4; ++n)
                    acc[r][n] = __builtin_amdgcn_mfma_f32_16x16x32_bf16(af[r], bfr[n], acc[r][n], 0, 0, 0);
        }
    }
    const float* bias = gb.bias[z];
    #pragma unroll
    for (int n = 0; n < 4; ++n) {
        const int nn = n0 + nrow0 + (n << 4) + l15;
        #pragma unroll
        for (int r = 0; r < 4; ++r) {
            const int mm = m0 + mrow0 + (r << 4) + (l4 << 2);
            f32x4 v = acc[r][n];
            if (EP == 1 || EP == 2) {
                #pragma unroll
                for (int j = 0; j < 4; ++j) v[j] = eluf(v[j] + bias[mm + j]);
            }
            if (EP == 1 || EP == 3) {
                unsigned lo = (unsigned)f2bf(v[0]) | ((unsigned)f2bf(v[1]) << 16);
                unsigned hi = (unsigned)f2bf(v[2]) | ((unsigned)f2bf(v[3]) << 16);
                *(uint2*)((u16*)gb.C[z] + (size_t)nn * ldo + mm) = make_uint2(lo, hi);
            } else {
                *(f32x4*)((float*)gb.C[z] + (size_t)nn * ldo + mm) = v;
            }
        }
    }
}

// ---------------- MFMA att with on-the-fly weights, j-split partials ----------------
// partial[blockIdx.z][i][c] = sum_{j in chunk} (sum_hd att_hd[i][j]) hT[c][j]
// blockIdx.z = ch * NZ + zj ; each z-slice is a full [N][Ncols] fp32 buffer.
template<int ACT, int NH, int NZ>
__global__ __launch_bounds__(256)
void att_mfma(const u16* __restrict__ hT, const float* __restrict__ s1b,
              const float* __restrict__ s2b, const float* __restrict__ qb,
              const u64* __restrict__ bits, float* __restrict__ out, int Ncols)
{
    __shared__ u16 Wl[128 * 64];
    __shared__ u16 Al[128 * 64];
    __shared__ float s1s[NH][128];
    __shared__ float qs[NH][128];
    constexpr int JT = 64 / NZ;           // j-tiles per block
    const int t    = threadIdx.x;
    const int i0   = blockIdx.x * 128;
    const int c0   = blockIdx.y * 128;
    const int ch   = blockIdx.z / NZ;
    const int zj   = blockIdx.z % NZ;
    const int jt0  = zj * JT;
    const int lane = t & 63, wv = t >> 6;
    const int l15  = lane & 15, l4 = lane >> 4;
    const int sblk = t & 7, srow = t >> 3;
    const float* s1p = s1b + (size_t)ch * NH * N_NODES;
    const float* s2p = s2b + (size_t)ch * NH * N_NODES;
    const float* qp  = qb  + (size_t)ch * NH * N_NODES;
    const u16* hTp   = hT  + (size_t)ch * Ncols * N_NODES;
    float* op        = out + (size_t)blockIdx.z * N_NODES * Ncols;

    for (int u = t; u < NH * 128; u += 256) {
        int hd = u >> 7, iL = u & 127;
        s1s[hd][iL] = s1p[hd * N_NODES + i0 + iL];
        qs[hd][iL]  = qp[hd * N_NODES + i0 + iL];
    }

    f32x4 acc[4][4] = {};
    const int mrow0 = 64 * (wv & 1);      // c-dim base
    const int nrow0 = 64 * (wv >> 1);     // i-dim base

    for (int jt = jt0; jt < jt0 + JT; ++jt) {
        const int j0 = jt << 6;
        __syncthreads();
        // phase W: generate combined softmax weights -> Wl (rows = iL, cols = j)
        float s2v[NH];
        #pragma unroll
        for (int hd = 0; hd < NH; ++hd) s2v[hd] = s2p[hd * N_NODES + j0 + lane];
        #pragma unroll 4
        for (int rr = 0; rr < 32; ++rr) {
            const int iL = (rr << 2) | wv;
            const u64 wd = bits[((size_t)(i0 + iL) << 6) + jt];
            float w = 0.f;
            if ((wd >> lane) & 1ull) {
                #pragma unroll
                for (int hd = 0; hd < NH; ++hd)
                    w += __expf(actf<ACT>(s1s[hd][iL] + s2v[hd]) - qs[hd][iL]);
            }
            Wl[iL * 64 + (lane ^ ((iL & 7) << 3))] = f2bf(w);
        }
        // phase A: stage hT[c0..+128][j0..+64]
        #pragma unroll
        for (int q = 0; q < 4; ++q) {
            const int row = srow + (q << 5);
            const uint4 v = *(const uint4*)(hTp + (size_t)(c0 + row) * N_NODES + j0 + (sblk << 3));
            *(uint4*)&Al[row * 64 + ((sblk << 3) ^ ((row & 7) << 3))] = v;
        }
        __syncthreads();
        // phase MFMA
        #pragma unroll
        for (int kk = 0; kk < 2; ++kk) {
            bf16x8 af[4], bfr[4];
            const int colu = (l4 << 3) + (kk << 5);
            #pragma unroll
            for (int r = 0; r < 4; ++r) {
                const int row = mrow0 + (r << 4) + l15;
                af[r] = *(const bf16x8*)&Al[row * 64 + (colu ^ ((row & 7) << 3))];
            }
            #pragma unroll
            for (int n = 0; n < 4; ++n) {
                const int row = nrow0 + (n << 4) + l15;
                bfr[n] = *(const bf16x8*)&Wl[row * 64 + (colu ^ ((row & 7) << 3))];
            }
            #pragma unroll
            for (int r = 0; r < 4; ++r)
                #pragma unroll
                for (int n = 0; n < 4; ++n)
                    acc[r][n] = __builtin_amdgcn_mfma_f32_16x16x32_bf16(af[r], bfr[n], acc[r][n], 0, 0, 0);
        }
    }
    // plain coalesced stores to this block's partial slice
    #pragma unroll
    for (int n = 0; n < 4; ++n) {
        const int i = i0 + nrow0 + (n << 4) + l15;
        #pragma unroll
        for (int r = 0; r < 4; ++r) {
            const int c = c0 + mrow0 + (r << 4) + (l4 << 2);
            *(f32x4*)&op[(size_t)i * Ncols + c] = acc[r][n];
        }
    }
}

// ---------------- GAT reduce (all 3 ch): xacc = sum_ch l2norm(elu(0.99(p0+p1)+0.01h)) + b ----------------
__global__ __launch_bounds__(128)
void reduce_gat_all(const float* __restrict__ partial, const u16* __restrict__ hT,
                    const float* __restrict__ gat_b, float* __restrict__ xacc)
{
    __shared__ float red[3][2];
    const int i = blockIdx.x, t = threadIdx.x;
    float v[3][3];
    #pragma unroll
    for (int ch = 0; ch < 3; ++ch) {
        const float* p0 = partial + ((size_t)(ch * 2 + 0) * N_NODES + i) * H1;
        const float* p1 = partial + ((size_t)(ch * 2 + 1) * N_NODES + i) * H1;
        const u16*   hp = hT + (size_t)ch * H1 * N_NODES;
        float ss = 0.f;
        #pragma unroll
        for (int u = 0; u < 3; ++u) {
            const int c = t + u * 128;
            float hv = bf2f(hp[(size_t)c * N_NODES + i]);
            float vv = eluf(0.99f * (p0[c] + p1[c]) + 0.01f * hv);
            v[ch][u] = vv; ss += vv * vv;
        }
        ss = waveReduceSum(ss);
        if ((t & 63) == 0) red[ch][t >> 6] = ss;
    }
    __syncthreads();
    float inv[3];
    #pragma unroll
    for (int ch = 0; ch < 3; ++ch)
        inv[ch] = 1.f / fmaxf(sqrtf(red[ch][0] + red[ch][1]), 1e-12f);
    #pragma unroll
    for (int u = 0; u < 3; ++u) {
        const int c = t + u * 128;
        float o = 0.f;
        #pragma unroll
        for (int ch = 0; ch < 3; ++ch)
            o += v[ch][u] * inv[ch] + gat_b[ch * H1 + c];
        xacc[(size_t)i * H1 + c] = o;
    }
}

// ---------------- conv(K=129, 3 ch) + elu + channel-combine -> hcore ----------------
__global__ __launch_bounds__(256)
void conv_combine(const float* __restrict__ xacc, const float* __restrict__ w_mid,
                  const float* __restrict__ b_mid, const float* __restrict__ w_core,
                  const float* __restrict__ b_core, float* __restrict__ hcore)
{
    __shared__ float row[H1];
    __shared__ float wm[3 * K_MID];
    const int n = blockIdx.x, t = threadIdx.x;
    for (int k = t; k < H1; k += 256) row[k] = eluf(xacc[(size_t)n * H1 + k] * (1.f / 3.f));
    for (int k = t; k < 3 * K_MID; k += 256) wm[k] = w_mid[k];
    __syncthreads();
    const int w = t;
    float a0 = 0.f, a1 = 0.f, a2 = 0.f;
    for (int k = 0; k < K_MID; ++k) {
        float xv = row[w + k];
        a0 += xv * wm[k];
        a1 += xv * wm[K_MID + k];
        a2 += xv * wm[2 * K_MID + k];
    }
    float hv = eluf(a0 + b_mid[0]) * w_core[0]
             + eluf(a1 + b_mid[1]) * w_core[1]
             + eluf(a2 + b_mid[2]) * w_core[2] + b_core[0];
    hcore[(size_t)n * H2 + w] = hv;
}

// ---------------- core reduce: embed_bf = bf16(l2norm(elu(0.125*Σz p + 0.5*hcore)) + cbias) ----------------
__global__ __launch_bounds__(256)
void reduce_core(const float* __restrict__ partial, const float* __restrict__ hcore,
                 const float* __restrict__ cbias, u16* __restrict__ embed_bf)
{
    __shared__ float red[4];
    const int i = blockIdx.x, t = threadIdx.x;
    float s = 0.f;
    #pragma unroll
    for (int zz = 0; zz < 8; ++zz)
        s += partial[((size_t)zz * N_NODES + i) * H2 + t];
    float v = eluf(0.125f * s + 0.5f * hcore[(size_t)i * H2 + t]);
    float ss = waveReduceSum(v * v);
    if ((t & 63) == 0) red[t >> 6] = ss;
    __syncthreads();
    float inv = 1.f / fmaxf(sqrtf(red[0] + red[1] + red[2] + red[3]), 1e-12f);
    embed_bf[(size_t)i * H2 + t] = f2bf(v * inv + cbias[t]);
}

// ---------------- pred[e] = tf[src[e]] . tg[dst[e]] ----------------
__global__ __launch_bounds__(256)
void gather_dot(const float* __restrict__ tf, const float* __restrict__ tg,
                const int* __restrict__ ts, float* __restrict__ pred)
{
    const int e = blockIdx.x * 4 + (threadIdx.x >> 6);
    const int lane = threadIdx.x & 63;
    const int i0 = ts[(size_t)e * 2], i1 = ts[(size_t)e * 2 + 1];
    const float* a = tf + (size_t)i0 * D_OUT;
    const float* b = tg + (size_t)i1 * D_OUT;
    float p = a[lane] * b[lane] + a[lane + 64] * b[lane + 64];
    p = waveReduceSum(p);
    if (lane == 0) pred[e] = p;
}

// ---------------- launch ----------------
extern "C" void kernel_launch(void* const* d_in, const int* in_sizes, int n_in,
                              void* d_out, int out_size, void* d_ws, size_t ws_size,
                              hipStream_t stream)
{
    const float* x1     = (const float*)d_in[0];
    const float* x2     = (const float*)d_in[1];
    const float* x3     = (const float*)d_in[2];
    const int*   adj    = (const int*)d_in[3];
    const int*   ts     = (const int*)d_in[4];
    const float* gat_W  = (const float*)d_in[5];
    const float* gat_a  = (const float*)d_in[6];
    const float* gat_b  = (const float*)d_in[7];
    const float* w_mid  = (const float*)d_in[8];
    const float* b_mid  = (const float*)d_in[9];
    const float* w_core = (const float*)d_in[10];
    const float* b_core = (const float*)d_in[11];
    const float* a_core = (const float*)d_in[12];
    const float* cbias  = (const float*)d_in[13];
    const float* W_tf1  = (const float*)d_in[14];
    const float* b_tf1  = (const float*)d_in[15];
    const float* W_tf2  = (const float*)d_in[16];
    const float* b_tf2  = (const float*)d_in[17];
    const float* W_tg1  = (const float*)d_in[18];
    const float* b_tg1  = (const float*)d_in[19];
    const float* W_tg2  = (const float*)d_in[20];
    const float* b_tg2  = (const float*)d_in[21];

    // ---- workspace layout (float units), ~62 MB ----
    const int NWORDS = N_NODES * (N_NODES / 64);        // 262144 u64
    float* fw    = (float*)d_ws;
    u64*   bits  = (u64*)d_ws;                          // 524288 fl
    float* s1b   = fw + 524288;                         // 16384
    float* s2b   = s1b + 16384;                         // 16384
    float* qb    = s2b + 16384;                         // 16384
    float* Wa    = qb + 16384;                          // 4608
    float* WTgF  = Wa + 4608;                           // 442368 (WTg | WT_mlp)
    float* hTF   = WTgF + 442368;                       // 2359296 (hT | hcoreT+embed_bf)
    float* xacc  = hTF + 2359296;                       // 1572864
    float* hcore = xacc + 1572864;                      // 1048576
    float* PART  = hcore + 1048576;                     // 9437184 (xb | GAT part | core part | t1/tf/tg)

    u16* xb      = (u16*)PART;                          // 3 x 4096x768 bf16 (dead before att)
    float* partial = PART;                              // GAT: 6 x N*H1 ; core: 8 x N*H2
    u16* t1tf    = (u16*)PART;                          // after reduce_core
    u16* t1tg    = (u16*)(PART + 1048576);
    float* tf    = PART + 2097152;
    float* tg    = PART + 2621440;
    u16* hT      = (u16*)hTF;                           // 3 x 384x4096 bf16
    u16* hcoreT  = (u16*)hTF;                           // 256x4096 bf16 (after GAT)
    u16* embed_bf= (u16*)(hTF + 524288);                // 4096x256 bf16
    u16* WTg     = (u16*)WTgF;                          // 3 x 384x768 bf16
    u16* WT1tf   = WTg;                                 // after gemm_h: 512x256
    u16* WT1tg   = WTg + 131072;
    u16* WT2tf   = WTg + 262144;                        // 128x512
    u16* WT2tg   = WTg + 327680;
    float* pred  = (float*)d_out;

    const dim3 blk(256);
    const size_t HSZ = (size_t)N_NODES * H1;

    // ---- prep ----
    pack_adj<<<dim3(1024), blk, 0, stream>>>(adj, bits, NWORDS);
    {   // gat_W -> WTg (bf16, [c][k])
        TP tp; for (int c = 0; c < 3; ++c) { tp.s[c] = gat_W + (size_t)c * D_IN * H1; tp.d[c] = WTg + (size_t)c * H1 * D_IN; }
        transpose_cvt<<<dim3(12, 6, 3), blk, 0, stream>>>(tp, D_IN, H1);
    }
    wa_pre<<<dim3(3, 3), blk, 0, stream>>>(gat_W, gat_a, Wa);
    XP3 xp; xp.x[0] = x1; xp.x[1] = x2; xp.x[2] = x3;
    cvt_x<<<dim3(768, 3), blk, 0, stream>>>(xp, xb);

    // ---- h^T = (x @ W)^T in bf16 via MFMA ----
    {
        GB gb;
        for (int c = 0; c < 3; ++c) {
            gb.A[c] = xb + (size_t)c * N_NODES * D_IN;
            gb.B[c] = WTg + (size_t)c * H1 * D_IN;
            gb.bias[c] = nullptr;
            gb.C[c] = hT + (size_t)c * HSZ;
        }
        gemm_bf16<3><<<dim3(32, 3, 3), blk, 0, stream>>>(gb, D_IN, N_NODES);
    }
    {   // mlp weight transposes (WTg region now reusable)
        TP tp; tp.s[0] = W_tf1; tp.s[1] = W_tg1; tp.d[0] = WT1tf; tp.d[1] = WT1tg;
        transpose_cvt<<<dim3(4, 8, 2), blk, 0, stream>>>(tp, H2, H3);
        TP tq; tq.s[0] = W_tf2; tq.s[1] = W_tg2; tq.d[0] = WT2tf; tq.d[1] = WT2tg;
        transpose_cvt<<<dim3(8, 2, 2), blk, 0, stream>>>(tq, H3, D_OUT);
    }

    // ---- GAT logits (exact fp32 via x @ (W@a)) + stats ----
    xdot<<<dim3(N_NODES, 3), dim3(64), 0, stream>>>(xp, Wa, s1b, s2b);
    softmax_stats<0><<<dim3(N_NODES, 3), blk, 0, stream>>>(s1b, s2b, bits, qb);

    // ---- GAT attention (3 channels batched, NZ=2 j-split, partial stores) ----
    att_mfma<0, 1, 2><<<dim3(32, 3, 6), blk, 0, stream>>>(hT, s1b, s2b, qb, bits, partial, H1);
    reduce_gat_all<<<dim3(N_NODES), dim3(128), 0, stream>>>(partial, hT, gat_b, xacc);

    // ---- conv + combine ----
    conv_combine<<<dim3(N_NODES), blk, 0, stream>>>(xacc, w_mid, b_mid, w_core, b_core, hcore);

    // ---- core attention (4 heads collapsed, NZ=8 j-split) ----
    rowdot2<<<dim3(N_NODES, 4), dim3(64), 0, stream>>>(hcore, 0, a_core, H2, s1b, s2b);
    softmax_stats<1><<<dim3(N_NODES, 4), blk, 0, stream>>>(s1b, s2b, bits, qb);
    {
        TP tp; tp.s[0] = hcore; tp.d[0] = hcoreT;
        transpose_cvt<<<dim3(64, 4, 1), blk, 0, stream>>>(tp, N_NODES, H2);
    }
    att_mfma<1, 4, 8><<<dim3(32, 2, 8), blk, 0, stream>>>(hcoreT, s1b, s2b, qb, bits, partial, H2);
    reduce_core<<<dim3(N_NODES), blk, 0, stream>>>(partial, hcore, cbias, embed_bf);

    // ---- final MLPs (bf16 MFMA, tf/tg batched) ----
    {
        GB gb;
        gb.A[0] = WT1tf; gb.A[1] = WT1tg;
        gb.B[0] = embed_bf; gb.B[1] = embed_bf;
        gb.bias[0] = b_tf1; gb.bias[1] = b_tg1;
        gb.C[0] = t1tf; gb.C[1] = t1tg;
        gemm_bf16<1><<<dim3(4, 32, 2), blk, 0, stream>>>(gb, H2, H3);
    }
    {
        GB gb;
        gb.A[0] = WT2tf; gb.A[1] = WT2tg;
        gb.B[0] = t1tf; gb.B[1] = t1tg;
        gb.bias[0] = b_tf2; gb.bias[1] = b_tg2;
        gb.C[0] = tf; gb.C[1] = tg;
        gemm_bf16<2><<<dim3(1, 32, 2), blk, 0, stream>>>(gb, H3, D_OUT);
    }
    gather_dot<<<dim3(E_EDGES / 4), blk, 0, stream>>>(tf, tg, ts, pred);
}

// Round 8
// 657.680 us; speedup vs baseline: 1.9345x; 1.2896x over previous
//
#include <hip/hip_runtime.h>
#include <math.h>

// ---------------- constants (match reference) ----------------
#define N_NODES 4096
#define D_IN    768
#define H1      384
#define H2      256
#define H3      512
#define D_OUT   128
#define E_EDGES 8192
#define K_MID   129
#define ALPHA   0.2f
#define NEGV    -9000000000000000.0f

typedef unsigned long long u64;
typedef unsigned short u16;
typedef __attribute__((ext_vector_type(8))) short bf16x8;
typedef __attribute__((ext_vector_type(4))) float f32x4;

// ---------------- helpers ----------------
__device__ __forceinline__ float eluf(float x) {          // precise (epilogues)
    return x > 0.f ? x : expm1f(x);
}

template<int ACT>  // 0 = leaky_relu(0.2), 1 = elu  (fast path, softmax logits)
__device__ __forceinline__ float actf(float x) {
    if (ACT == 0) return fmaxf(x, ALPHA * x);             // leaky = max(x, 0.2x)
    else          return x > 0.f ? x : __expf(x) - 1.f;
}

__device__ __forceinline__ u16 f2bf(float f) {            // RNE fp32 -> bf16 bits
    unsigned u = __float_as_uint(f);
    unsigned r = (u + 0x7FFFu + ((u >> 16) & 1u)) >> 16;
    return (u16)r;
}
__device__ __forceinline__ float bf2f(u16 h) {
    return __uint_as_float(((unsigned)h) << 16);
}

__device__ __forceinline__ float waveReduceMax(float v) {
    #pragma unroll
    for (int off = 32; off; off >>= 1) v = fmaxf(v, __shfl_xor(v, off));
    return v;
}
__device__ __forceinline__ float waveReduceSum(float v) {
    #pragma unroll
    for (int off = 32; off; off >>= 1) v += __shfl_xor(v, off);
    return v;
}

// ---------------- pack adj into bitmask (row-major + transposed) ----------------
__global__ __launch_bounds__(256)
void pack_adj(const int* __restrict__ adj, u64* __restrict__ bits,
              u64* __restrict__ bitsT, int nwords) {
    int wid  = (blockIdx.x * 256 + threadIdx.x) >> 6;
    int lane = threadIdx.x & 63;
    int nw   = (gridDim.x * 256) >> 6;
    for (int w = wid; w < nwords; w += nw) {
        u64 m = __ballot(adj[((size_t)w << 6) + lane] > 0);
        if (lane == 0) {
            bits[w] = m;                                      // [i][jw]
            bitsT[(size_t)(w & 63) * N_NODES + (w >> 6)] = m; // [jw][i]
        }
    }
}

// ---------------- generic transpose + cvt: dst[c][r] = bf16(src[r][c]) ----------------
struct TP { const float* s[3]; u16* d[3]; };
__global__ __launch_bounds__(256)
void transpose_cvt(TP tp, int R, int C)
{
    __shared__ float tile[64][65];
    const int z = blockIdx.z;
    const float* __restrict__ src = tp.s[z];
    u16* __restrict__ dst = tp.d[z];
    const int j0 = blockIdx.x * 64, c0 = blockIdx.y * 64;
    const int t = threadIdx.x;
    #pragma unroll
    for (int q = 0; q < 16; ++q) {
        int idx = q * 256 + t;
        int jl = idx >> 6, cl = idx & 63;
        tile[jl][cl] = src[(size_t)(j0 + jl) * C + c0 + cl];
    }
    __syncthreads();
    #pragma unroll
    for (int q = 0; q < 16; ++q) {
        int idx = q * 256 + t;
        int cl = idx >> 6, jl = idx & 63;
        dst[(size_t)(c0 + cl) * R + j0 + jl] = f2bf(tile[jl][cl]);
    }
}

// ---------------- Wa[ch][0/1][k] = sum_c W[ch][k][c] * a[ch][c or H1+c] ----------------
__global__ __launch_bounds__(256)
void wa_pre(const float* __restrict__ gat_W, const float* __restrict__ gat_a,
            float* __restrict__ Wa)
{
    const int ch = blockIdx.y;
    const int k  = blockIdx.x * 256 + threadIdx.x;        // 0..767
    const float* wr = gat_W + ((size_t)ch * D_IN + k) * H1;
    const float* a  = gat_a + (size_t)ch * 2 * H1;
    float w1 = 0.f, w2 = 0.f;
    for (int c = 0; c < H1; ++c) { float wv = wr[c]; w1 += wv * a[c]; w2 += wv * a[H1 + c]; }
    Wa[(size_t)ch * 2 * D_IN + k]        = w1;
    Wa[(size_t)ch * 2 * D_IN + D_IN + k] = w2;
}

// ---------------- x (fp32) -> xb (bf16, same layout) ----------------
struct XP3 { const float* x[3]; };
__global__ __launch_bounds__(256)
void cvt_x(XP3 xp, u16* __restrict__ xb)
{
    const int ch = blockIdx.y;
    const float* s = xp.x[ch];
    u16* d = xb + (size_t)ch * N_NODES * D_IN;
    const int n4 = N_NODES * D_IN / 4;
    for (int idx = blockIdx.x * 256 + threadIdx.x; idx < n4; idx += gridDim.x * 256) {
        float4 v = ((const float4*)s)[idx];
        unsigned lo = (unsigned)f2bf(v.x) | ((unsigned)f2bf(v.y) << 16);
        unsigned hi = (unsigned)f2bf(v.z) | ((unsigned)f2bf(v.w) << 16);
        ((uint2*)d)[idx] = make_uint2(lo, hi);
    }
}

// ---------------- s1/s2 = x @ Wa (fp32, exact logits) ----------------
__global__ __launch_bounds__(64)
void xdot(XP3 xp, const float* __restrict__ Wa,
          float* __restrict__ s1b, float* __restrict__ s2b)
{
    const int i = blockIdx.x, ch = blockIdx.y, lane = threadIdx.x;
    const float* xr = xp.x[ch] + (size_t)i * D_IN;
    const float* w1 = Wa + (size_t)ch * 2 * D_IN;
    const float* w2 = w1 + D_IN;
    float p1 = 0.f, p2 = 0.f;
    for (int k = lane; k < D_IN; k += 64) { float xv = xr[k]; p1 += xv * w1[k]; p2 += xv * w2[k]; }
    p1 = waveReduceSum(p1);
    p2 = waveReduceSum(p2);
    if (lane == 0) { s1b[ch * N_NODES + i] = p1; s2b[ch * N_NODES + i] = p2; }
}

// ---------------- batched row dots (core: hcore @ a_core) ----------------
__global__ __launch_bounds__(64)
void rowdot2(const float* __restrict__ hbase, size_t hStride,
             const float* __restrict__ ab, int K,
             float* __restrict__ s1b, float* __restrict__ s2b)
{
    const int i = blockIdx.x, z = blockIdx.y, lane = threadIdx.x;
    const float* hp = hbase + (size_t)z * hStride + (size_t)i * K;
    const float* a  = ab + (size_t)z * 2 * K;
    float p1 = 0.f, p2 = 0.f;
    for (int k = lane; k < K; k += 64) {
        float hv = hp[k];
        p1 += hv * a[k];
        p2 += hv * a[K + k];
    }
    p1 = waveReduceSum(p1);
    p2 = waveReduceSum(p2);
    if (lane == 0) { s1b[z * N_NODES + i] = p1; s2b[z * N_NODES + i] = p2; }
}

// ---------------- per-row softmax stats: q[z][i] = M + ln(Z) ----------------
template<int ACT>
__global__ __launch_bounds__(256)
void softmax_stats(const float* __restrict__ s1b, const float* __restrict__ s2b,
                   const u64* __restrict__ bits, float* __restrict__ qb)
{
    __shared__ float lsh[N_NODES];
    __shared__ float red[8];
    const int i = blockIdx.x, z = blockIdx.y, t = threadIdx.x;
    const float s1v = s1b[z * N_NODES + i];
    const float* s2 = s2b + (size_t)z * N_NODES;
    float mx = -3.0e38f;
    for (int j = t; j < N_NODES; j += 256) {
        u64 wd = bits[((size_t)i << 6) + (j >> 6)];
        float l = ((wd >> (j & 63)) & 1ull) ? actf<ACT>(s1v + s2[j]) : NEGV;
        lsh[j] = l;
        mx = fmaxf(mx, l);
    }
    mx = waveReduceMax(mx);
    if ((t & 63) == 0) red[t >> 6] = mx;
    __syncthreads();
    float M = fmaxf(fmaxf(red[0], red[1]), fmaxf(red[2], red[3]));
    float sum = 0.f;
    for (int j = t; j < N_NODES; j += 256) sum += __expf(lsh[j] - M);
    sum = waveReduceSum(sum);
    if ((t & 63) == 0) red[4 + (t >> 6)] = sum;
    __syncthreads();
    if (t == 0) {
        float Z = red[4] + red[5] + red[6] + red[7];
        qb[z * N_NODES + i] = M + logf(Z);
    }
}

// ---------------- generic bf16 MFMA GEMM: D[m][n] = sum_k A[m][k]*B[n][k] ----------------
// A: [M][K] bf16 k-contig.  B: [N][K] bf16 k-contig.  out[n*ldo + m] (m contiguous).
// EP: 0 raw fp32 | 1 elu(v+bias[m]) bf16 | 2 elu(v+bias[m]) fp32 | 3 raw bf16
struct GB {
    const u16* A[3];
    const u16* B[3];
    const float* bias[3];
    void* C[3];
};
template<int EP>
__global__ __launch_bounds__(256)
void gemm_bf16(GB gb, int K, int ldo)
{
    __shared__ u16 Al[128 * 64];
    __shared__ u16 Bl[128 * 64];
    const int z = blockIdx.z;
    const u16* __restrict__ A = gb.A[z];
    const u16* __restrict__ B = gb.B[z];
    const int t  = threadIdx.x;
    const int m0 = blockIdx.x * 128, n0 = blockIdx.y * 128;
    const int lane = t & 63, wv = t >> 6;
    const int l15 = lane & 15, l4 = lane >> 4;
    const int mrow0 = 64 * (wv & 1), nrow0 = 64 * (wv >> 1);
    const int sblk = t & 7, srow = t >> 3;
    f32x4 acc[4][4] = {};

    for (int k0 = 0; k0 < K; k0 += 64) {
        __syncthreads();
        #pragma unroll
        for (int q = 0; q < 4; ++q) {
            const int row = srow + (q << 5);
            const uint4 va = *(const uint4*)(A + (size_t)(m0 + row) * K + k0 + (sblk << 3));
            *(uint4*)&Al[row * 64 + ((sblk << 3) ^ ((row & 7) << 3))] = va;
            const uint4 vb = *(const uint4*)(B + (size_t)(n0 + row) * K + k0 + (sblk << 3));
            *(uint4*)&Bl[row * 64 + ((sblk << 3) ^ ((row & 7) << 3))] = vb;
        }
        __syncthreads();
        #pragma unroll
        for (int kk = 0; kk < 2; ++kk) {
            bf16x8 af[4], bfr[4];
            const int colu = (l4 << 3) + (kk << 5);
            #pragma unroll
            for (int r = 0; r < 4; ++r) {
                const int row = mrow0 + (r << 4) + l15;
                af[r] = *(const bf16x8*)&Al[row * 64 + (colu ^ ((row & 7) << 3))];
            }
            #pragma unroll
            for (int n = 0; n < 4; ++n) {
                const int row = nrow0 + (n << 4) + l15;
                bfr[n] = *(const bf16x8*)&Bl[row * 64 + (colu ^ ((row & 7) << 3))];
            }
            #pragma unroll
            for (int r = 0; r < 4; ++r)
                #pragma unroll
                for (int n = 0; n < 4; ++n)
                    acc[r][n] = __builtin_amdgcn_mfma_f32_16x16x32_bf16(af[r], bfr[n], acc[r][n], 0, 0, 0);
        }
    }
    const float* bias = gb.bias[z];
    #pragma unroll
    for (int n = 0; n < 4; ++n) {
        const int nn = n0 + nrow0 + (n << 4) + l15;
        #pragma unroll
        for (int r = 0; r < 4; ++r) {
            const int mm = m0 + mrow0 + (r << 4) + (l4 << 2);
            f32x4 v = acc[r][n];
            if (EP == 1 || EP == 2) {
                #pragma unroll
                for (int j = 0; j < 4; ++j) v[j] = eluf(v[j] + bias[mm + j]);
            }
            if (EP == 1 || EP == 3) {
                unsigned lo = (unsigned)f2bf(v[0]) | ((unsigned)f2bf(v[1]) << 16);
                unsigned hi = (unsigned)f2bf(v[2]) | ((unsigned)f2bf(v[3]) << 16);
                *(uint2*)((u16*)gb.C[z] + (size_t)nn * ldo + mm) = make_uint2(lo, hi);
            } else {
                *(f32x4*)((float*)gb.C[z] + (size_t)nn * ldo + mm) = v;
            }
        }
    }
}

// ---------------- MFMA att: 64-row x FULL-column blocks, W-gen once per (i,j) ----------------
// partial[(ch*NZ+zj)][i][c] = sum_{j in chunk zj} (sum_hd att_hd[i][j]) hT[c][j]
// Grid: (64 i-tiles, n_ch, NZ).  NCOLS = full column count (384 / 256).
template<int ACT, int NH, int NZ, int NCOLS>
__global__ __launch_bounds__(256)
void att_mfma(const u16* __restrict__ hT, const float* __restrict__ s1b,
              const float* __restrict__ s2b, const float* __restrict__ qb,
              const u64* __restrict__ bitsT, float* __restrict__ out)
{
    constexpr int JT  = 64 / NZ;          // j-tiles per block
    constexpr int WC  = NCOLS / 4;        // cols per wave (96 / 64)
    constexpr int NFR = WC / 16;          // m-fragments per wave (6 / 4)
    __shared__ u16 Wl[64 * 64];           // weights [iL][j] swizzled (8KB)
    __shared__ u16 Al[NCOLS * 64];        // hT tile [c][j] swizzled
    __shared__ float s1s[NH][64];
    __shared__ float qs[NH][64];
    const int t    = threadIdx.x;
    const int i0   = blockIdx.x * 64;
    const int ch   = blockIdx.y;
    const int zj   = blockIdx.z;
    const int jt0  = zj * JT;
    const int lane = t & 63, wv = t >> 6;
    const int l15  = lane & 15, l4 = lane >> 4;
    const int sblk = t & 7, srow = t >> 3;
    const float* s1p = s1b + (size_t)ch * NH * N_NODES;
    const float* s2p = s2b + (size_t)ch * NH * N_NODES;
    const float* qp  = qb  + (size_t)ch * NH * N_NODES;
    const u16* hTp   = hT  + (size_t)ch * NCOLS * N_NODES;
    float* op        = out + (size_t)(ch * NZ + zj) * N_NODES * NCOLS;

    if (t < NH * 64) {
        int hd = t >> 6, iL = t & 63;
        s1s[hd][iL] = s1p[hd * N_NODES + i0 + iL];
        qs[hd][iL]  = qp[hd * N_NODES + i0 + iL];
    }

    f32x4 acc[NFR][4] = {};

    for (int jt = jt0; jt < jt0 + JT; ++jt) {
        const int j0 = jt << 6;
        // preload this tile's mask words (lanes 0..15, distributed via shfl)
        u64 wd_l = 0;
        if (lane < 16) wd_l = bitsT[(size_t)jt * N_NODES + i0 + (lane << 2) + wv];
        float s2v[NH];
        #pragma unroll
        for (int hd = 0; hd < NH; ++hd) s2v[hd] = s2p[hd * N_NODES + j0 + lane];
        __syncthreads();                   // LDS free (prev MFMA done; covers s1s on iter 0)
        // stage hT[0..NCOLS)[j0..j0+64)
        #pragma unroll
        for (int p = 0; p < NCOLS / 32; ++p) {
            const int row = srow + (p << 5);
            const uint4 v = *(const uint4*)(hTp + (size_t)row * N_NODES + j0 + (sblk << 3));
            *(uint4*)&Al[row * 64 + ((sblk << 3) ^ ((row & 7) << 3))] = v;
        }
        // W-gen: 16 rows per wave (iL = 4*rr + wv), col = lane
        #pragma unroll
        for (int rr = 0; rr < 16; ++rr) {
            const int iL = (rr << 2) | wv;
            const u64 wd = __shfl(wd_l, rr);
            float w = 0.f;
            #pragma unroll
            for (int hd = 0; hd < NH; ++hd)
                w += __expf(actf<ACT>(s1s[hd][iL] + s2v[hd]) - qs[hd][iL]);
            w = ((wd >> lane) & 1ull) ? w : 0.f;
            Wl[iL * 64 + (lane ^ ((iL & 7) << 3))] = f2bf(w);
        }
        __syncthreads();
        // MFMA: D[m=c][n=i] over the wave's column range
        #pragma unroll
        for (int kk = 0; kk < 2; ++kk) {
            const int colu = (l4 << 3) + (kk << 5);
            bf16x8 bfr[4];
            #pragma unroll
            for (int n = 0; n < 4; ++n) {
                const int row = (n << 4) + l15;
                bfr[n] = *(const bf16x8*)&Wl[row * 64 + (colu ^ ((row & 7) << 3))];
            }
            #pragma unroll
            for (int f = 0; f < NFR; ++f) {
                const int row = wv * WC + (f << 4) + l15;
                bf16x8 af = *(const bf16x8*)&Al[row * 64 + (colu ^ ((row & 7) << 3))];
                #pragma unroll
                for (int n = 0; n < 4; ++n)
                    acc[f][n] = __builtin_amdgcn_mfma_f32_16x16x32_bf16(af, bfr[n], acc[f][n], 0, 0, 0);
            }
        }
    }
    // coalesced stores to this block's partial slice
    #pragma unroll
    for (int n = 0; n < 4; ++n) {
        const int i = i0 + (n << 4) + l15;
        #pragma unroll
        for (int f = 0; f < NFR; ++f) {
            const int c = wv * WC + (f << 4) + (l4 << 2);
            *(f32x4*)&op[(size_t)i * NCOLS + c] = acc[f][n];
        }
    }
}

// ---------------- GAT reduce (all 3 ch): xacc = sum_ch l2norm(elu(0.99(p0+p1)+0.01h)) + b ----------------
__global__ __launch_bounds__(128)
void reduce_gat_all(const float* __restrict__ partial, const u16* __restrict__ hT,
                    const float* __restrict__ gat_b, float* __restrict__ xacc)
{
    __shared__ float red[3][2];
    const int i = blockIdx.x, t = threadIdx.x;
    float v[3][3];
    #pragma unroll
    for (int ch = 0; ch < 3; ++ch) {
        const float* p0 = partial + ((size_t)(ch * 2 + 0) * N_NODES + i) * H1;
        const float* p1 = partial + ((size_t)(ch * 2 + 1) * N_NODES + i) * H1;
        const u16*   hp = hT + (size_t)ch * H1 * N_NODES;
        float ss = 0.f;
        #pragma unroll
        for (int u = 0; u < 3; ++u) {
            const int c = t + u * 128;
            float hv = bf2f(hp[(size_t)c * N_NODES + i]);
            float vv = eluf(0.99f * (p0[c] + p1[c]) + 0.01f * hv);
            v[ch][u] = vv; ss += vv * vv;
        }
        ss = waveReduceSum(ss);
        if ((t & 63) == 0) red[ch][t >> 6] = ss;
    }
    __syncthreads();
    float inv[3];
    #pragma unroll
    for (int ch = 0; ch < 3; ++ch)
        inv[ch] = 1.f / fmaxf(sqrtf(red[ch][0] + red[ch][1]), 1e-12f);
    #pragma unroll
    for (int u = 0; u < 3; ++u) {
        const int c = t + u * 128;
        float o = 0.f;
        #pragma unroll
        for (int ch = 0; ch < 3; ++ch)
            o += v[ch][u] * inv[ch] + gat_b[ch * H1 + c];
        xacc[(size_t)i * H1 + c] = o;
    }
}

// ---------------- conv(K=129, 3 ch) + elu + channel-combine -> hcore ----------------
__global__ __launch_bounds__(256)
void conv_combine(const float* __restrict__ xacc, const float* __restrict__ w_mid,
                  const float* __restrict__ b_mid, const float* __restrict__ w_core,
                  const float* __restrict__ b_core, float* __restrict__ hcore)
{
    __shared__ float row[H1];
    __shared__ float wm[3 * K_MID];
    const int n = blockIdx.x, t = threadIdx.x;
    for (int k = t; k < H1; k += 256) row[k] = eluf(xacc[(size_t)n * H1 + k] * (1.f / 3.f));
    for (int k = t; k < 3 * K_MID; k += 256) wm[k] = w_mid[k];
    __syncthreads();
    const int w = t;
    float a0 = 0.f, a1 = 0.f, a2 = 0.f;
    for (int k = 0; k < K_MID; ++k) {
        float xv = row[w + k];
        a0 += xv * wm[k];
        a1 += xv * wm[K_MID + k];
        a2 += xv * wm[2 * K_MID + k];
    }
    float hv = eluf(a0 + b_mid[0]) * w_core[0]
             + eluf(a1 + b_mid[1]) * w_core[1]
             + eluf(a2 + b_mid[2]) * w_core[2] + b_core[0];
    hcore[(size_t)n * H2 + w] = hv;
}

// ---------------- core reduce: embed_bf = bf16(l2norm(elu(0.125*Σz p + 0.5*hcore)) + cbias) ----------------
__global__ __launch_bounds__(256)
void reduce_core(const float* __restrict__ partial, const float* __restrict__ hcore,
                 const float* __restrict__ cbias, u16* __restrict__ embed_bf)
{
    __shared__ float red[4];
    const int i = blockIdx.x, t = threadIdx.x;
    float s = 0.f;
    #pragma unroll
    for (int zz = 0; zz < 8; ++zz)
        s += partial[((size_t)zz * N_NODES + i) * H2 + t];
    float v = eluf(0.125f * s + 0.5f * hcore[(size_t)i * H2 + t]);
    float ss = waveReduceSum(v * v);
    if ((t & 63) == 0) red[t >> 6] = ss;
    __syncthreads();
    float inv = 1.f / fmaxf(sqrtf(red[0] + red[1] + red[2] + red[3]), 1e-12f);
    embed_bf[(size_t)i * H2 + t] = f2bf(v * inv + cbias[t]);
}

// ---------------- pred[e] = tf[src[e]] . tg[dst[e]] ----------------
__global__ __launch_bounds__(256)
void gather_dot(const float* __restrict__ tf, const float* __restrict__ tg,
                const int* __restrict__ ts, float* __restrict__ pred)
{
    const int e = blockIdx.x * 4 + (threadIdx.x >> 6);
    const int lane = threadIdx.x & 63;
    const int i0 = ts[(size_t)e * 2], i1 = ts[(size_t)e * 2 + 1];
    const float* a = tf + (size_t)i0 * D_OUT;
    const float* b = tg + (size_t)i1 * D_OUT;
    float p = a[lane] * b[lane] + a[lane + 64] * b[lane + 64];
    p = waveReduceSum(p);
    if (lane == 0) pred[e] = p;
}

// ---------------- launch ----------------
extern "C" void kernel_launch(void* const* d_in, const int* in_sizes, int n_in,
                              void* d_out, int out_size, void* d_ws, size_t ws_size,
                              hipStream_t stream)
{
    const float* x1     = (const float*)d_in[0];
    const float* x2     = (const float*)d_in[1];
    const float* x3     = (const float*)d_in[2];
    const int*   adj    = (const int*)d_in[3];
    const int*   ts     = (const int*)d_in[4];
    const float* gat_W  = (const float*)d_in[5];
    const float* gat_a  = (const float*)d_in[6];
    const float* gat_b  = (const float*)d_in[7];
    const float* w_mid  = (const float*)d_in[8];
    const float* b_mid  = (const float*)d_in[9];
    const float* w_core = (const float*)d_in[10];
    const float* b_core = (const float*)d_in[11];
    const float* a_core = (const float*)d_in[12];
    const float* cbias  = (const float*)d_in[13];
    const float* W_tf1  = (const float*)d_in[14];
    const float* b_tf1  = (const float*)d_in[15];
    const float* W_tf2  = (const float*)d_in[16];
    const float* b_tf2  = (const float*)d_in[17];
    const float* W_tg1  = (const float*)d_in[18];
    const float* b_tg1  = (const float*)d_in[19];
    const float* W_tg2  = (const float*)d_in[20];
    const float* b_tg2  = (const float*)d_in[21];

    // ---- workspace layout (float units), ~64 MB ----
    const int NWORDS = N_NODES * (N_NODES / 64);        // 262144 u64
    float* fw    = (float*)d_ws;
    u64*   bits  = (u64*)d_ws;                          // 524288 fl
    u64*   bitsT = (u64*)(fw + 524288);                 // 524288 fl
    float* s1b   = fw + 1048576;                        // 16384
    float* s2b   = s1b + 16384;                         // 16384
    float* qb    = s2b + 16384;                         // 16384
    float* Wa    = qb + 16384;                          // 4608
    float* WTgF  = Wa + 4608;                           // 442368 (WTg | WT_mlp)
    float* hTF   = WTgF + 442368;                       // 2359296 (hT | hcoreT+embed_bf)
    float* xacc  = hTF + 2359296;                       // 1572864
    float* hcore = xacc + 1572864;                      // 1048576
    float* PART  = hcore + 1048576;                     // 9437184 (xb | GAT part | core part | t1/tf/tg)

    u16* xb      = (u16*)PART;                          // 3 x 4096x768 bf16 (dead before att)
    float* partial = PART;                              // GAT: 6 x N*H1 ; core: 8 x N*H2
    u16* t1tf    = (u16*)PART;                          // after reduce_core
    u16* t1tg    = (u16*)(PART + 1048576);
    float* tf    = PART + 2097152;
    float* tg    = PART + 2621440;
    u16* hT      = (u16*)hTF;                           // 3 x 384x4096 bf16
    u16* hcoreT  = (u16*)hTF;                           // 256x4096 bf16 (after GAT)
    u16* embed_bf= (u16*)(hTF + 524288);                // 4096x256 bf16
    u16* WTg     = (u16*)WTgF;                          // 3 x 384x768 bf16
    u16* WT1tf   = WTg;                                 // after gemm_h: 512x256
    u16* WT1tg   = WTg + 131072;
    u16* WT2tf   = WTg + 262144;                        // 128x512
    u16* WT2tg   = WTg + 327680;
    float* pred  = (float*)d_out;

    const dim3 blk(256);
    const size_t HSZ = (size_t)N_NODES * H1;

    // ---- prep ----
    pack_adj<<<dim3(1024), blk, 0, stream>>>(adj, bits, bitsT, NWORDS);
    {   // gat_W -> WTg (bf16, [c][k])
        TP tp; for (int c = 0; c < 3; ++c) { tp.s[c] = gat_W + (size_t)c * D_IN * H1; tp.d[c] = WTg + (size_t)c * H1 * D_IN; }
        transpose_cvt<<<dim3(12, 6, 3), blk, 0, stream>>>(tp, D_IN, H1);
    }
    wa_pre<<<dim3(3, 3), blk, 0, stream>>>(gat_W, gat_a, Wa);
    XP3 xp; xp.x[0] = x1; xp.x[1] = x2; xp.x[2] = x3;
    cvt_x<<<dim3(768, 3), blk, 0, stream>>>(xp, xb);

    // ---- h^T = (x @ W)^T in bf16 via MFMA ----
    {
        GB gb;
        for (int c = 0; c < 3; ++c) {
            gb.A[c] = xb + (size_t)c * N_NODES * D_IN;
            gb.B[c] = WTg + (size_t)c * H1 * D_IN;
            gb.bias[c] = nullptr;
            gb.C[c] = hT + (size_t)c * HSZ;
        }
        gemm_bf16<3><<<dim3(32, 3, 3), blk, 0, stream>>>(gb, D_IN, N_NODES);
    }
    {   // mlp weight transposes (WTg region now reusable)
        TP tp; tp.s[0] = W_tf1; tp.s[1] = W_tg1; tp.d[0] = WT1tf; tp.d[1] = WT1tg;
        transpose_cvt<<<dim3(4, 8, 2), blk, 0, stream>>>(tp, H2, H3);
        TP tq; tq.s[0] = W_tf2; tq.s[1] = W_tg2; tq.d[0] = WT2tf; tq.d[1] = WT2tg;
        transpose_cvt<<<dim3(8, 2, 2), blk, 0, stream>>>(tq, H3, D_OUT);
    }

    // ---- GAT logits (exact fp32 via x @ (W@a)) + stats ----
    xdot<<<dim3(N_NODES, 3), dim3(64), 0, stream>>>(xp, Wa, s1b, s2b);
    softmax_stats<0><<<dim3(N_NODES, 3), blk, 0, stream>>>(s1b, s2b, bits, qb);

    // ---- GAT attention (64-row full-column blocks, NZ=2, partial stores) ----
    att_mfma<0, 1, 2, H1><<<dim3(64, 3, 2), blk, 0, stream>>>(hT, s1b, s2b, qb, bitsT, partial);
    reduce_gat_all<<<dim3(N_NODES), dim3(128), 0, stream>>>(partial, hT, gat_b, xacc);

    // ---- conv + combine ----
    conv_combine<<<dim3(N_NODES), blk, 0, stream>>>(xacc, w_mid, b_mid, w_core, b_core, hcore);

    // ---- core attention (4 heads collapsed, NZ=8) ----
    rowdot2<<<dim3(N_NODES, 4), dim3(64), 0, stream>>>(hcore, 0, a_core, H2, s1b, s2b);
    softmax_stats<1><<<dim3(N_NODES, 4), blk, 0, stream>>>(s1b, s2b, bits, qb);
    {
        TP tp; tp.s[0] = hcore; tp.d[0] = hcoreT;
        transpose_cvt<<<dim3(64, 4, 1), blk, 0, stream>>>(tp, N_NODES, H2);
    }
    att_mfma<1, 4, 8, H2><<<dim3(64, 1, 8), blk, 0, stream>>>(hcoreT, s1b, s2b, qb, bitsT, partial);
    reduce_core<<<dim3(N_NODES), blk, 0, stream>>>(partial, hcore, cbias, embed_bf);

    // ---- final MLPs (bf16 MFMA, tf/tg batched) ----
    {
        GB gb;
        gb.A[0] = WT1tf; gb.A[1] = WT1tg;
        gb.B[0] = embed_bf; gb.B[1] = embed_bf;
        gb.bias[0] = b_tf1; gb.bias[1] = b_tg1;
        gb.C[0] = t1tf; gb.C[1] = t1tg;
        gemm_bf16<1><<<dim3(4, 32, 2), blk, 0, stream>>>(gb, H2, H3);
    }
    {
        GB gb;
        gb.A[0] = WT2tf; gb.A[1] = WT2tg;
        gb.B[0] = t1tf; gb.B[1] = t1tg;
        gb.bias[0] = b_tf2; gb.bias[1] = b_tg2;
        gb.C[0] = tf; gb.C[1] = tg;
        gemm_bf16<2><<<dim3(1, 32, 2), blk, 0, stream>>>(gb, H3, D_OUT);
    }
    gather_dot<<<dim3(E_EDGES / 4), blk, 0, stream>>>(tf, tg, ts, pred);
}